// Round 6
// baseline (464.610 us; speedup 1.0000x reference)
//
#include <hip/hip_runtime.h>

#define BB 8
#define LL 512
#define HH 8
#define BIGV (1e9f)

typedef unsigned short u16;
typedef __attribute__((ext_vector_type(8))) short bf16x8;
typedef __attribute__((ext_vector_type(4))) short s16x4;
typedef __attribute__((ext_vector_type(4))) float f32x4;

#define MFMA(a,b,c) __builtin_amdgcn_mfma_f32_16x16x32_bf16(a,b,c,0,0,0)

__device__ __forceinline__ u16 f2b(float f){
  unsigned u = __float_as_uint(f);
  u = (u + 0x7fffu + ((u>>16)&1u)) >> 16;
  return (u16)u;
}
__device__ __forceinline__ float b2f(u16 s){ return __uint_as_float(((unsigned)s)<<16); }
__device__ __forceinline__ bf16x8 ldb8(const u16* p){ return *(const bf16x8*)p; }
// non-temporal (streaming) accesses: keep L2 for reused operands (t2t/qzb)
__device__ __forceinline__ bf16x8 ldb8nt(const u16* p){ return __builtin_nontemporal_load((const bf16x8*)p); }
__device__ __forceinline__ f32x4 ldf4nt(const float* p){ return __builtin_nontemporal_load((const f32x4*)p); }
__device__ __forceinline__ void stb8nt(u16* p, bf16x8 v){ __builtin_nontemporal_store(v, (bf16x8*)p); }
__device__ __forceinline__ void st4nt(u16* p, s16x4 v){ __builtin_nontemporal_store(v, (s16x4*)p); }

__device__ __forceinline__ float wred_max(float v){
  #pragma unroll
  for(int off=32;off>0;off>>=1) v = fmaxf(v, __shfl_xor(v, off, 64));
  return v;
}
__device__ __forceinline__ float wred_sum(float v){
  #pragma unroll
  for(int off=32;off>0;off>>=1) v += __shfl_xor(v, off, 64);
  return v;
}
__device__ __forceinline__ float g16_sum(float v){
  v += __shfl_xor(v,1,64); v += __shfl_xor(v,2,64);
  v += __shfl_xor(v,4,64); v += __shfl_xor(v,8,64);
  return v;
}

// ---- tables: T4t[c][b][a], Tt2[c][a][b], Gt[a][j], Gt2[j][a] ----
__global__ void kp_prep(const float* __restrict__ T, const float* __restrict__ gw,
                        u16* __restrict__ T4t, u16* __restrict__ Tt2,
                        u16* __restrict__ Gt, u16* __restrict__ Gt2){
  int idx = blockIdx.x*256 + threadIdx.x;   // < 32768
  { int c=idx>>12, b=(idx>>6)&63, a=idx&63; T4t[idx] = f2b(T[(a*64+b)*8+c]); }
  { int c=idx>>12, a=(idx>>6)&63, b=idx&63; Tt2[idx] = f2b(T[(a*64+b)*8+c]); }
  if(idx < 4096){
    int a=idx>>6, j=idx&63;
    Gt[idx]  = f2b(gw[j*64+a]);   // Gt[a][j]
    Gt2[idx] = f2b(gw[idx]);      // Gt2[j][a]
  }
}

// ---- k0: unary = (x+pe)*m1 ; qzstate = unary ; mf = mask as float ----
__global__ void k0_init(const float* __restrict__ x, const int* __restrict__ mask,
                        float* __restrict__ unary, float* __restrict__ qzstate,
                        float* __restrict__ mf){
  int idx = blockIdx.x*256 + threadIdx.x;
  int d = idx & 63; int row = idx >> 6;
  int pos = row & (LL-1);
  int k2 = d & ~1;
  float div = __expf(-(float)k2 * 0.14391156962f);  // ln(10000)/64
  float arg = (float)pos * div;
  float pe = (d & 1) ? cosf(arg) : sinf(arg);
  float mk = (mask[row] != 0) ? 1.f : 0.f;
  float u = (x[idx] + pe) * mk;
  unary[idx] = u; qzstate[idx] = u;
  if(d == 0) mf[row] = mk;
}

// ---- kA: softmax64 -> qzb ; P2 softmax + Mg = P2@gw -> MgF ----
__global__ __launch_bounds__(256) void kA(const float* __restrict__ qzstate,
      const int* __restrict__ mask, const u16* __restrict__ Gt2, const u16* __restrict__ Gt,
      u16* __restrict__ qzb, float* __restrict__ MgF){
  __shared__ u16 qlds[64*72];
  __shared__ u16 P2s[64*72];
  int bid = blockIdx.x; int z = bid & 7, itile = bid >> 3;   // z-affine for XCD L2
  int t = threadIdx.x, lane = t&63, w = t>>6, l15 = lane&15, lhi = lane>>4;
  int rbase = z*LL + itile*64;
  for(int p=0;p<16;p++){
    int rl = w*16 + p, rg = rbase + rl;
    float v = qzstate[(size_t)rg*64 + lane];
    float mx = wred_max(v);
    float e = __expf(v - mx);
    float s = wred_sum(e);
    float mk = (mask[rg] != 0) ? 1.f : 0.f;
    u16 q = f2b(e/s*mk);
    qzb[(size_t)rg*64 + lane] = q;
    qlds[rl*72 + lane] = q;
  }
  __syncthreads();
  // P2 = rowsoftmax(qz @ gw^T)  (logits bounded ~|gw| -> fixed-max exp)
  f32x4 f[4];
  {
    const u16* Ar = &qlds[(w*16 + l15)*72 + lhi*8];
    bf16x8 a0 = ldb8(Ar), a1 = ldb8(Ar+32);
    #pragma unroll
    for(int ct=0;ct<4;ct++){
      const u16* Br = Gt2 + (size_t)(ct*16 + l15)*64 + lhi*8;
      f32x4 acc = {0.f,0.f,0.f,0.f};
      acc = MFMA(a0, ldb8(Br), acc);
      acc = MFMA(a1, ldb8(Br+32), acc);
      f[ct] = acc;
    }
  }
  #pragma unroll
  for(int jj=0;jj<4;jj++){
    float ps = 0.f;
    #pragma unroll
    for(int ct=0;ct<4;ct++){ float e = __expf(f[ct][jj]); f[ct][jj] = e; ps += e; }
    float s = g16_sum(ps);
    float iv = 1.f/s;
    #pragma unroll
    for(int ct=0;ct<4;ct++)
      P2s[(w*16 + lhi*4 + jj)*72 + ct*16 + l15] = f2b(f[ct][jj]*iv);
  }
  __syncthreads();
  // Mg[i,a] = sum_j P2[i,j] gw[j,a]  (B = Gt[a][j])
  {
    const u16* Ar = &P2s[(w*16 + l15)*72 + lhi*8];
    bf16x8 a0 = ldb8(Ar), a1 = ldb8(Ar+32);
    #pragma unroll
    for(int nt=0;nt<4;nt++){
      const u16* Br = Gt + (size_t)(nt*16 + l15)*64 + lhi*8;
      f32x4 acc = {0.f,0.f,0.f,0.f};
      acc = MFMA(a0, ldb8(Br), acc);
      acc = MFMA(a1, ldb8(Br+32), acc);
      #pragma unroll
      for(int jj=0;jj<4;jj++)
        MgF[((size_t)rbase + w*16 + lhi*4 + jj)*64 + nt*16 + l15] = acc[jj];
    }
  }
}

// ---- k2: per (z,c): t1[i][b], t1t[b][i], t2t[a][j]  (all K=64 GEMMs) ----
__global__ __launch_bounds__(256) void k2(const u16* __restrict__ qzb,
      const u16* __restrict__ T4t, const u16* __restrict__ Tt2,
      u16* __restrict__ t1b, u16* __restrict__ t1t, u16* __restrict__ t2t){
  int bid = blockIdx.x; int z = bid&7, c = (bid>>3)&7, itile = bid>>6;
  int zc = z*8 + c;
  int t = threadIdx.x, lane = t&63, w = t>>6, l15 = lane&15, lhi = lane>>4;
  int i0 = itile*64;
  const u16* qA = qzb + ((size_t)z*LL + i0 + w*16 + l15)*64 + lhi*8;
  bf16x8 qa0 = ldb8(qA), qa1 = ldb8(qA+32);
  const u16* tA = T4t + c*4096 + (w*16 + l15)*64 + lhi*8;
  bf16x8 ta0 = ldb8(tA), ta1 = ldb8(tA+32);
  const u16* uA = Tt2 + c*4096 + (w*16 + l15)*64 + lhi*8;
  bf16x8 ua0 = ldb8(uA), ua1 = ldb8(uA+32);
  #pragma unroll
  for(int nt=0;nt<4;nt++){
    { // t1 = qz @ T_c : B rows = T4t[c][b][a]
      const u16* Br = T4t + c*4096 + (nt*16 + l15)*64 + lhi*8;
      f32x4 acc = {0.f,0.f,0.f,0.f};
      acc = MFMA(qa0, ldb8(Br), acc);
      acc = MFMA(qa1, ldb8(Br+32), acc);
      #pragma unroll
      for(int jj=0;jj<4;jj++)
        t1b[((size_t)zc*LL + i0 + w*16 + lhi*4 + jj)*64 + nt*16 + l15] = f2b(acc[jj]);
    }
    const u16* Br = qzb + ((size_t)z*LL + i0 + nt*16 + l15)*64 + lhi*8;
    bf16x8 qb0 = ldb8(Br), qb1 = ldb8(Br+32);
    { // t1t[b][i]
      f32x4 acc = {0.f,0.f,0.f,0.f};
      acc = MFMA(ta0, qb0, acc);
      acc = MFMA(ta1, qb1, acc);
      #pragma unroll
      for(int jj=0;jj<4;jj++)
        t1t[((size_t)zc*64 + w*16 + lhi*4 + jj)*LL + i0 + nt*16 + l15] = f2b(acc[jj]);
    }
    { // t2t[a][j]
      f32x4 acc = {0.f,0.f,0.f,0.f};
      acc = MFMA(ua0, qb0, acc);
      acc = MFMA(ua1, qb1, acc);
      #pragma unroll
      for(int jj=0;jj<4;jj++)
        t2t[((size_t)zc*64 + w*16 + lhi*4 + jj)*LL + i0 + nt*16 + l15] = f2b(acc[jj]);
    }
  }
}

// ---- kF: fused S -> P -> mi = P@t2t (complete) + mj-partials = P^T@t1t ----
// read-once streams (t1b, t1t) and write-once outputs (miP, mjP) are non-temporal
// so the reused operands (t2t, qzb) stay resident in the XCD L2.
__global__ __launch_bounds__(1024) void kF(const u16* __restrict__ t1b, const u16* __restrict__ qzb,
        const u16* __restrict__ t1t, const u16* __restrict__ t2t, const float* __restrict__ mf,
        u16* __restrict__ miP, u16* __restrict__ mjP){
  extern __shared__ char smem[];
  u16*   Pp   = (u16*)smem;                   // [32][520]   33280 B
  u16*   PpT  = (u16*)(smem + 33280);         // [512][40]   40960 B
  float* red  = (float*)(smem + 74240);       // [32][16]     2048 B
  float* stgf = (float*)(smem + 76288);       // [2][32][68] f32 (17408 B)
  u16*   stg  = (u16*)(smem + 76288);         // [128][72] u16   (18432 B)
  int bid = blockIdx.x;
  int z = bid&7, c = (bid>>3)&7, it = bid>>6;   // it < 4
  int zc = z*8 + c;
  int t = threadIdx.x, lane = t&63, w = t>>6, l15 = lane&15, lhi = lane>>4;
  int jc0 = w*32;                               // wave's j-slice
  float mfj[2];
  mfj[0] = mf[z*LL + jc0 + l15];
  mfj[1] = mf[z*LL + jc0 + 16 + l15];
  f32x4 mj[2][4];
  #pragma unroll
  for(int jt=0;jt<2;jt++)
    #pragma unroll
    for(int bt=0;bt<4;bt++) mj[jt][bt] = (f32x4){0.f,0.f,0.f,0.f};

  for(int ip=0; ip<4; ++ip){
    int i0g = it*128 + ip*32;
    // ---- S panel (32 rows x wave's 32 cols) ----
    f32x4 S[2][2];
    #pragma unroll
    for(int rt=0;rt<2;rt++){ S[rt][0] = (f32x4){0,0,0,0}; S[rt][1] = (f32x4){0,0,0,0}; }
    bf16x8 a0[2], a1[2];
    #pragma unroll
    for(int rt=0;rt<2;rt++){
      const u16* Ar = t1b + ((size_t)zc*LL + i0g + rt*16 + l15)*64 + lhi*8;
      a0[rt] = ldb8nt(Ar); a1[rt] = ldb8nt(Ar+32);
    }
    #pragma unroll
    for(int ct=0;ct<2;ct++){
      const u16* Br = qzb + ((size_t)z*LL + jc0 + ct*16 + l15)*64 + lhi*8;
      bf16x8 b0 = ldb8(Br), b1 = ldb8(Br+32);
      #pragma unroll
      for(int rt=0;rt<2;rt++){
        S[rt][ct] = MFMA(a0[rt], b0, S[rt][ct]);
        S[rt][ct] = MFMA(a1[rt], b1, S[rt][ct]);
      }
    }
    // ---- mask/diag/exp (fixed max), partial row-sums ----
    #pragma unroll
    for(int rt=0;rt<2;rt++)
      #pragma unroll
      for(int jj=0;jj<4;jj++){
        int rloc = rt*16 + lhi*4 + jj;
        int irow = i0g + rloc;
        float mfi = mf[z*LL + irow];
        float ps = 0.f;
        #pragma unroll
        for(int ct=0;ct<2;ct++){
          int jcol = jc0 + ct*16 + l15;
          float v = S[rt][ct][jj] - ((irow==jcol)?BIGV:0.f);
          float e = mfi * mfj[ct] * __expf(v);
          S[rt][ct][jj] = e; ps += e;
        }
        ps = g16_sum(ps);
        if(l15 == 0) red[rloc*16 + w] = ps;
      }
    __syncthreads();
    // ---- normalize, write Pp (row-major) + PpT (transposed) ----
    #pragma unroll
    for(int rt=0;rt<2;rt++){
      float iv[4];
      #pragma unroll
      for(int jj=0;jj<4;jj++){
        const float* rp = &red[(rt*16 + lhi*4 + jj)*16];
        f32x4 s0 = *(const f32x4*)rp,      s1 = *(const f32x4*)(rp+4);
        f32x4 s2 = *(const f32x4*)(rp+8),  s3 = *(const f32x4*)(rp+12);
        float s = (s0[0]+s0[1]+s0[2]+s0[3]) + (s1[0]+s1[1]+s1[2]+s1[3])
                + (s2[0]+s2[1]+s2[2]+s2[3]) + (s3[0]+s3[1]+s3[2]+s3[3]);
        iv[jj] = s > 0.f ? 1.f/s : 0.f;
      }
      #pragma unroll
      for(int ct=0;ct<2;ct++){
        int jcol = jc0 + ct*16 + l15;
        u16 p4[4];
        #pragma unroll
        for(int jj=0;jj<4;jj++){
          u16 pb = f2b(S[rt][ct][jj]*iv[jj]);
          Pp[(rt*16 + lhi*4 + jj)*520 + jcol] = pb;
          p4[jj] = pb;
        }
        s16x4 v4 = {(short)p4[0],(short)p4[1],(short)p4[2],(short)p4[3]};
        *(s16x4*)&PpT[(size_t)jcol*40 + rt*16 + lhi*4] = v4;
      }
    }
    __syncthreads();
    // ---- mi: (h,wr,wc) split, half-K each; partials to stgf ----
    {
      int h = w>>3, wr = (w>>2)&1, wc = w&3;
      f32x4 mia = {0.f,0.f,0.f,0.f};
      const u16* Ab = Pp + (wr*16 + l15)*520 + h*256 + lhi*8;
      const u16* Bb = t2t + ((size_t)zc*64 + wc*16 + l15)*LL + h*256 + lhi*8;
      #pragma unroll
      for(int ks=0;ks<8;ks++)
        mia = MFMA(ldb8(Ab + ks*32), ldb8(Bb + ks*32), mia);
      #pragma unroll
      for(int jj=0;jj<4;jj++)
        stgf[(h*32 + wr*16 + lhi*4 + jj)*68 + wc*16 + l15] = mia[jj];
    }
    // ---- mj accumulate: K=32 (this panel), A = PpT, B = t1t (nt stream) ----
    {
      bf16x8 av[2];
      #pragma unroll
      for(int jt=0;jt<2;jt++)
        av[jt] = ldb8(PpT + (size_t)(jc0 + jt*16 + l15)*40 + lhi*8);
      #pragma unroll
      for(int bt=0;bt<4;bt++){
        bf16x8 b = ldb8nt(t1t + ((size_t)zc*64 + bt*16 + l15)*LL + i0g + lhi*8);
        #pragma unroll
        for(int jt=0;jt<2;jt++) mj[jt][bt] = MFMA(av[jt], b, mj[jt][bt]);
      }
    }
    __syncthreads();
    // ---- mi store: sum 2 K-halves, 16B coalesced, streaming ----
    if(t < 512){
      int r = t>>4, cc = t&15;
      f32x4 v0 = *(const f32x4*)&stgf[r*68 + cc*4];
      f32x4 v1 = *(const f32x4*)&stgf[(32+r)*68 + cc*4];
      s16x4 o = { (short)f2b(v0[0]+v1[0]), (short)f2b(v0[1]+v1[1]),
                  (short)f2b(v0[2]+v1[2]), (short)f2b(v0[3]+v1[3]) };
      st4nt(&miP[((size_t)z*LL + i0g + r)*512 + c*64 + cc*4], o);
    }
    __syncthreads();
  }
  // ---- mj dump: 4 rounds of 128 j-rows via LDS, 16B coalesced, streaming ----
  for(int r=0;r<4;r++){
    if((w>>2) == r){
      int jl = (w&3)*32;
      #pragma unroll
      for(int jt=0;jt<2;jt++)
        #pragma unroll
        for(int bt=0;bt<4;bt++)
          #pragma unroll
          for(int jj=0;jj<4;jj++)
            stg[(jl + jt*16 + lhi*4 + jj)*72 + bt*16 + l15] = f2b(mj[jt][bt][jj]);
    }
    __syncthreads();
    {
      int jr = t>>3, ch = t&7;
      stb8nt(&mjP[(((size_t)(it*8 + z))*LL + r*128 + jr)*512 + c*64 + ch*8],
             *(const bf16x8*)&stg[jr*72 + ch*8]);
    }
    __syncthreads();
  }
}

// ---- k5c: out = (unary + Mg + sum_c miP + sum_{it,c} mjP) * m1  (elementwise) ----
__global__ __launch_bounds__(256) void k5c(const u16* __restrict__ miP, const u16* __restrict__ mjP,
      const float* __restrict__ MgF, const float* __restrict__ unary, const float* __restrict__ mf,
      float* __restrict__ outq){
  int bid = blockIdx.x; int z = bid&7, itile = bid>>3;   // itile < 16
  int t = threadIdx.x;
  int r = t>>3, c8 = t&7;
  int row = itile*32 + r;
  size_t gr = (size_t)z*LL + row;
  const float* mgp = &MgF[gr*64 + c8*8];
  f32x4 aclo = ldf4nt(mgp);
  f32x4 achi = ldf4nt(mgp + 4);
  #pragma unroll
  for(int c=0;c<8;c++){
    bf16x8 v = ldb8nt(&miP[gr*512 + c*64 + c8*8]);
    aclo[0]+=b2f((u16)v[0]); aclo[1]+=b2f((u16)v[1]); aclo[2]+=b2f((u16)v[2]); aclo[3]+=b2f((u16)v[3]);
    achi[0]+=b2f((u16)v[4]); achi[1]+=b2f((u16)v[5]); achi[2]+=b2f((u16)v[6]); achi[3]+=b2f((u16)v[7]);
  }
  #pragma unroll
  for(int s=0;s<4;s++)
    #pragma unroll
    for(int c=0;c<8;c++){
      bf16x8 v = ldb8nt(&mjP[(((size_t)(s*8 + z))*LL + row)*512 + c*64 + c8*8]);
      aclo[0]+=b2f((u16)v[0]); aclo[1]+=b2f((u16)v[1]); aclo[2]+=b2f((u16)v[2]); aclo[3]+=b2f((u16)v[3]);
      achi[0]+=b2f((u16)v[4]); achi[1]+=b2f((u16)v[5]); achi[2]+=b2f((u16)v[6]); achi[3]+=b2f((u16)v[7]);
    }
  f32x4 u0 = *(const f32x4*)&unary[gr*64 + c8*8];
  f32x4 u1 = *(const f32x4*)&unary[gr*64 + c8*8 + 4];
  float mk = mf[gr];
  f32x4 o0, o1;
  #pragma unroll
  for(int k=0;k<4;k++){ o0[k] = (u0[k] + aclo[k]) * mk; o1[k] = (u1[k] + achi[k]) * mk; }
  *(f32x4*)&outq[gr*64 + c8*8]     = o0;
  *(f32x4*)&outq[gr*64 + c8*8 + 4] = o1;
}

extern "C" void kernel_launch(void* const* d_in, const int* in_sizes, int n_in,
                              void* d_out, int out_size, void* d_ws, size_t ws_size,
                              hipStream_t stream) {
  const float* x       = (const float*)d_in[0];
  const int*   mask    = (const int*)d_in[1];
  const float* ternary = (const float*)d_in[2];
  const float* gw      = (const float*)d_in[3];
  float* out = (float*)d_out;

  const size_t NE = (size_t)BB*LL*64;          // 262144
  char* p = (char*)d_ws;
  auto alloc = [&](size_t bytes)->void*{
    void* r = (void*)p; p += (bytes + 255) & ~(size_t)255; return r;
  };
  float* unary   = (float*)alloc(NE*4);
  float* qzstate = (float*)alloc(NE*4);
  float* mf      = (float*)alloc((size_t)BB*LL*4);
  u16*   qzb     = (u16*)alloc(NE*2);
  u16*   t1b     = (u16*)alloc((size_t)BB*HH*LL*64*2);   // 4.2 MB
  u16*   t1t     = (u16*)alloc((size_t)BB*HH*LL*64*2);   // 4.2 MB
  u16*   t2t     = (u16*)alloc((size_t)BB*HH*LL*64*2);   // 4.2 MB
  float* MgF     = (float*)alloc(NE*4);                  // 1 MB
  u16*   miP     = (u16*)alloc((size_t)BB*LL*512*2);     // 4.2 MB
  u16*   mjP     = (u16*)alloc((size_t)32*LL*512*2);     // 16.8 MB
  u16*   T4t     = (u16*)alloc(32768*2);
  u16*   Tt2     = (u16*)alloc(32768*2);
  u16*   Gt      = (u16*)alloc(4096*2);
  u16*   Gt2     = (u16*)alloc(4096*2);

  const int KF_LDS = 94720;
  hipFuncSetAttribute(reinterpret_cast<const void*>(kF),
                      hipFuncAttributeMaxDynamicSharedMemorySize, KF_LDS);

  kp_prep<<<128, 256, 0, stream>>>(ternary, gw, T4t, Tt2, Gt, Gt2);
  k0_init<<<(int)(NE/256), 256, 0, stream>>>(x, mask, unary, qzstate, mf);
  for(int it=0; it<4; ++it){
    kA<<<BB*8, 256, 0, stream>>>(qzstate, mask, Gt2, Gt, qzb, MgF);
    k2<<<512, 256, 0, stream>>>(qzb, T4t, Tt2, t1b, t1t, t2t);
    kF<<<256, 1024, KF_LDS, stream>>>(t1b, qzb, t1t, t2t, mf, miP, mjP);
    float* outq = (it==3) ? out : qzstate;
    k5c<<<128, 256, 0, stream>>>(miP, mjP, MgF, unary, mf, outq);
  }
}

// Round 7
// 343.516 us; speedup vs baseline: 1.3525x; 1.3525x over previous
//
#include <hip/hip_runtime.h>

#define BB 8
#define LL 512
#define HH 8
#define BIGV (1e9f)

typedef unsigned short u16;
typedef __attribute__((ext_vector_type(8))) short bf16x8;
typedef __attribute__((ext_vector_type(4))) short s16x4;
typedef __attribute__((ext_vector_type(4))) float f32x4;

#define MFMA(a,b,c) __builtin_amdgcn_mfma_f32_16x16x32_bf16(a,b,c,0,0,0)

__device__ __forceinline__ u16 f2b(float f){
  unsigned u = __float_as_uint(f);
  u = (u + 0x7fffu + ((u>>16)&1u)) >> 16;
  return (u16)u;
}
__device__ __forceinline__ float b2f(u16 s){ return __uint_as_float(((unsigned)s)<<16); }
__device__ __forceinline__ bf16x8 ldb8(const u16* p){ return *(const bf16x8*)p; }

__device__ __forceinline__ float wred_max(float v){
  #pragma unroll
  for(int off=32;off>0;off>>=1) v = fmaxf(v, __shfl_xor(v, off, 64));
  return v;
}
__device__ __forceinline__ float wred_sum(float v){
  #pragma unroll
  for(int off=32;off>0;off>>=1) v += __shfl_xor(v, off, 64);
  return v;
}
__device__ __forceinline__ float g16_sum(float v){
  v += __shfl_xor(v,1,64); v += __shfl_xor(v,2,64);
  v += __shfl_xor(v,4,64); v += __shfl_xor(v,8,64);
  return v;
}

// ---- tables: T4t[c][b][a], Tt2[c][a][b], Gt[a][j], Gt2[j][a] ----
__global__ void kp_prep(const float* __restrict__ T, const float* __restrict__ gw,
                        u16* __restrict__ T4t, u16* __restrict__ Tt2,
                        u16* __restrict__ Gt, u16* __restrict__ Gt2){
  int idx = blockIdx.x*256 + threadIdx.x;   // < 32768
  { int c=idx>>12, b=(idx>>6)&63, a=idx&63; T4t[idx] = f2b(T[(a*64+b)*8+c]); }
  { int c=idx>>12, a=(idx>>6)&63, b=idx&63; Tt2[idx] = f2b(T[(a*64+b)*8+c]); }
  if(idx < 4096){
    int a=idx>>6, j=idx&63;
    Gt[idx]  = f2b(gw[j*64+a]);   // Gt[a][j]
    Gt2[idx] = f2b(gw[idx]);      // Gt2[j][a]
  }
}

// ---- k0: unary = (x+pe)*m1 ; qzstate = unary ; mf = mask as float ----
__global__ void k0_init(const float* __restrict__ x, const int* __restrict__ mask,
                        float* __restrict__ unary, float* __restrict__ qzstate,
                        float* __restrict__ mf){
  int idx = blockIdx.x*256 + threadIdx.x;
  int d = idx & 63; int row = idx >> 6;
  int pos = row & (LL-1);
  int k2 = d & ~1;
  float div = __expf(-(float)k2 * 0.14391156962f);  // ln(10000)/64
  float arg = (float)pos * div;
  float pe = (d & 1) ? cosf(arg) : sinf(arg);
  float mk = (mask[row] != 0) ? 1.f : 0.f;
  float u = (x[idx] + pe) * mk;
  unary[idx] = u; qzstate[idx] = u;
  if(d == 0) mf[row] = mk;
}

// ---- kA: softmax64 -> qzb ; P2 softmax + Mg = P2@gw -> MgF ----
__global__ __launch_bounds__(256) void kA(const float* __restrict__ qzstate,
      const int* __restrict__ mask, const u16* __restrict__ Gt2, const u16* __restrict__ Gt,
      u16* __restrict__ qzb, float* __restrict__ MgF){
  __shared__ u16 qlds[64*72];
  __shared__ u16 P2s[64*72];
  int bid = blockIdx.x; int z = bid & 7, itile = bid >> 3;   // z-affine for XCD L2
  int t = threadIdx.x, lane = t&63, w = t>>6, l15 = lane&15, lhi = lane>>4;
  int rbase = z*LL + itile*64;
  for(int p=0;p<16;p++){
    int rl = w*16 + p, rg = rbase + rl;
    float v = qzstate[(size_t)rg*64 + lane];
    float mx = wred_max(v);
    float e = __expf(v - mx);
    float s = wred_sum(e);
    float mk = (mask[rg] != 0) ? 1.f : 0.f;
    u16 q = f2b(e/s*mk);
    qzb[(size_t)rg*64 + lane] = q;
    qlds[rl*72 + lane] = q;
  }
  __syncthreads();
  // P2 = rowsoftmax(qz @ gw^T)  (logits bounded ~|gw| -> fixed-max exp)
  f32x4 f[4];
  {
    const u16* Ar = &qlds[(w*16 + l15)*72 + lhi*8];
    bf16x8 a0 = ldb8(Ar), a1 = ldb8(Ar+32);
    #pragma unroll
    for(int ct=0;ct<4;ct++){
      const u16* Br = Gt2 + (size_t)(ct*16 + l15)*64 + lhi*8;
      f32x4 acc = {0.f,0.f,0.f,0.f};
      acc = MFMA(a0, ldb8(Br), acc);
      acc = MFMA(a1, ldb8(Br+32), acc);
      f[ct] = acc;
    }
  }
  #pragma unroll
  for(int jj=0;jj<4;jj++){
    float ps = 0.f;
    #pragma unroll
    for(int ct=0;ct<4;ct++){ float e = __expf(f[ct][jj]); f[ct][jj] = e; ps += e; }
    float s = g16_sum(ps);
    float iv = 1.f/s;
    #pragma unroll
    for(int ct=0;ct<4;ct++)
      P2s[(w*16 + lhi*4 + jj)*72 + ct*16 + l15] = f2b(f[ct][jj]*iv);
  }
  __syncthreads();
  // Mg[i,a] = sum_j P2[i,j] gw[j,a]  (B = Gt[a][j])
  {
    const u16* Ar = &P2s[(w*16 + l15)*72 + lhi*8];
    bf16x8 a0 = ldb8(Ar), a1 = ldb8(Ar+32);
    #pragma unroll
    for(int nt=0;nt<4;nt++){
      const u16* Br = Gt + (size_t)(nt*16 + l15)*64 + lhi*8;
      f32x4 acc = {0.f,0.f,0.f,0.f};
      acc = MFMA(a0, ldb8(Br), acc);
      acc = MFMA(a1, ldb8(Br+32), acc);
      #pragma unroll
      for(int jj=0;jj<4;jj++)
        MgF[((size_t)rbase + w*16 + lhi*4 + jj)*64 + nt*16 + l15] = acc[jj];
    }
  }
}

// ---- k2: per (z,c): t1[i][b], t1t[b][i], t2t[a][j]  (all K=64 GEMMs) ----
__global__ __launch_bounds__(256) void k2(const u16* __restrict__ qzb,
      const u16* __restrict__ T4t, const u16* __restrict__ Tt2,
      u16* __restrict__ t1b, u16* __restrict__ t1t, u16* __restrict__ t2t){
  int bid = blockIdx.x; int z = bid&7, c = (bid>>3)&7, itile = bid>>6;
  int zc = z*8 + c;
  int t = threadIdx.x, lane = t&63, w = t>>6, l15 = lane&15, lhi = lane>>4;
  int i0 = itile*64;
  const u16* qA = qzb + ((size_t)z*LL + i0 + w*16 + l15)*64 + lhi*8;
  bf16x8 qa0 = ldb8(qA), qa1 = ldb8(qA+32);
  const u16* tA = T4t + c*4096 + (w*16 + l15)*64 + lhi*8;
  bf16x8 ta0 = ldb8(tA), ta1 = ldb8(tA+32);
  const u16* uA = Tt2 + c*4096 + (w*16 + l15)*64 + lhi*8;
  bf16x8 ua0 = ldb8(uA), ua1 = ldb8(uA+32);
  #pragma unroll
  for(int nt=0;nt<4;nt++){
    { // t1 = qz @ T_c : B rows = T4t[c][b][a]
      const u16* Br = T4t + c*4096 + (nt*16 + l15)*64 + lhi*8;
      f32x4 acc = {0.f,0.f,0.f,0.f};
      acc = MFMA(qa0, ldb8(Br), acc);
      acc = MFMA(qa1, ldb8(Br+32), acc);
      #pragma unroll
      for(int jj=0;jj<4;jj++)
        t1b[((size_t)zc*LL + i0 + w*16 + lhi*4 + jj)*64 + nt*16 + l15] = f2b(acc[jj]);
    }
    const u16* Br = qzb + ((size_t)z*LL + i0 + nt*16 + l15)*64 + lhi*8;
    bf16x8 qb0 = ldb8(Br), qb1 = ldb8(Br+32);
    { // t1t[b][i]
      f32x4 acc = {0.f,0.f,0.f,0.f};
      acc = MFMA(ta0, qb0, acc);
      acc = MFMA(ta1, qb1, acc);
      #pragma unroll
      for(int jj=0;jj<4;jj++)
        t1t[((size_t)zc*64 + w*16 + lhi*4 + jj)*LL + i0 + nt*16 + l15] = f2b(acc[jj]);
    }
    { // t2t[a][j]
      f32x4 acc = {0.f,0.f,0.f,0.f};
      acc = MFMA(ua0, qb0, acc);
      acc = MFMA(ua1, qb1, acc);
      #pragma unroll
      for(int jj=0;jj<4;jj++)
        t2t[((size_t)zc*64 + w*16 + lhi*4 + jj)*LL + i0 + nt*16 + l15] = f2b(acc[jj]);
    }
  }
}

// ---- kF: fused S -> P -> mi = P@t2t (complete) + mj-partials = P^T@t1t ----
// t2t[zc] (64 KB) is LDS-staged once per block: the mi phase re-reads it 4x,
// which from global was 64 MB/launch of L2-miss traffic (round-5/6 lesson).
__global__ __launch_bounds__(1024) void kF(const u16* __restrict__ t1b, const u16* __restrict__ qzb,
        const u16* __restrict__ t1t, const u16* __restrict__ t2t, const float* __restrict__ mf,
        u16* __restrict__ miP, u16* __restrict__ mjP){
  extern __shared__ char smem[];
  u16*   t2s  = (u16*)smem;                    // [64][520]   66560 B
  u16*   Pp   = (u16*)(smem + 66560);          // [32][520]   33280 B
  u16*   PpT  = (u16*)(smem + 99840);          // [512][40]   40960 B
  float* red  = (float*)(smem + 140800);       // [32][16]     2048 B
  float* stgf = (float*)(smem + 142848);       // [2][32][68] f32 (17408 B)
  u16*   stg  = (u16*)(smem + 142848);         // [128][72] u16   (18432 B)
  int bid = blockIdx.x;
  int z = bid&7, c = (bid>>3)&7, it = bid>>6;   // it < 4
  int zc = z*8 + c;
  int t = threadIdx.x, lane = t&63, w = t>>6, l15 = lane&15, lhi = lane>>4;
  int jc0 = w*32;                               // wave's j-slice
  // ---- stage t2t[zc] -> LDS (4 passes x 1024 threads x 16B) ----
  #pragma unroll
  for(int m=0;m<4;m++){
    int e = (m*1024 + t)*8;          // element index, 8 elems per thread
    int a = e >> 9, j = e & 511;
    bf16x8 v = ldb8(t2t + ((size_t)zc*64 + a)*LL + j);
    *(bf16x8*)&t2s[a*520 + j] = v;
  }
  float mfj[2];
  mfj[0] = mf[z*LL + jc0 + l15];
  mfj[1] = mf[z*LL + jc0 + 16 + l15];
  f32x4 mj[2][4];
  #pragma unroll
  for(int jt=0;jt<2;jt++)
    #pragma unroll
    for(int bt=0;bt<4;bt++) mj[jt][bt] = (f32x4){0.f,0.f,0.f,0.f};

  for(int ip=0; ip<4; ++ip){
    int i0g = it*128 + ip*32;
    // ---- S panel (32 rows x wave's 32 cols) ----
    f32x4 S[2][2];
    #pragma unroll
    for(int rt=0;rt<2;rt++){ S[rt][0] = (f32x4){0,0,0,0}; S[rt][1] = (f32x4){0,0,0,0}; }
    bf16x8 a0[2], a1[2];
    #pragma unroll
    for(int rt=0;rt<2;rt++){
      const u16* Ar = t1b + ((size_t)zc*LL + i0g + rt*16 + l15)*64 + lhi*8;
      a0[rt] = ldb8(Ar); a1[rt] = ldb8(Ar+32);
    }
    #pragma unroll
    for(int ct=0;ct<2;ct++){
      const u16* Br = qzb + ((size_t)z*LL + jc0 + ct*16 + l15)*64 + lhi*8;
      bf16x8 b0 = ldb8(Br), b1 = ldb8(Br+32);
      #pragma unroll
      for(int rt=0;rt<2;rt++){
        S[rt][ct] = MFMA(a0[rt], b0, S[rt][ct]);
        S[rt][ct] = MFMA(a1[rt], b1, S[rt][ct]);
      }
    }
    // ---- mask/diag/exp (fixed max), partial row-sums ----
    #pragma unroll
    for(int rt=0;rt<2;rt++)
      #pragma unroll
      for(int jj=0;jj<4;jj++){
        int rloc = rt*16 + lhi*4 + jj;
        int irow = i0g + rloc;
        float mfi = mf[z*LL + irow];
        float ps = 0.f;
        #pragma unroll
        for(int ct=0;ct<2;ct++){
          int jcol = jc0 + ct*16 + l15;
          float v = S[rt][ct][jj] - ((irow==jcol)?BIGV:0.f);
          float e = mfi * mfj[ct] * __expf(v);
          S[rt][ct][jj] = e; ps += e;
        }
        ps = g16_sum(ps);
        if(l15 == 0) red[rloc*16 + w] = ps;
      }
    __syncthreads();
    // ---- normalize, write Pp (row-major) + PpT (transposed) ----
    #pragma unroll
    for(int rt=0;rt<2;rt++){
      float iv[4];
      #pragma unroll
      for(int jj=0;jj<4;jj++){
        const float* rp = &red[(rt*16 + lhi*4 + jj)*16];
        f32x4 s0 = *(const f32x4*)rp,      s1 = *(const f32x4*)(rp+4);
        f32x4 s2 = *(const f32x4*)(rp+8),  s3 = *(const f32x4*)(rp+12);
        float s = (s0[0]+s0[1]+s0[2]+s0[3]) + (s1[0]+s1[1]+s1[2]+s1[3])
                + (s2[0]+s2[1]+s2[2]+s2[3]) + (s3[0]+s3[1]+s3[2]+s3[3]);
        iv[jj] = s > 0.f ? 1.f/s : 0.f;
      }
      #pragma unroll
      for(int ct=0;ct<2;ct++){
        int jcol = jc0 + ct*16 + l15;
        u16 p4[4];
        #pragma unroll
        for(int jj=0;jj<4;jj++){
          u16 pb = f2b(S[rt][ct][jj]*iv[jj]);
          Pp[(rt*16 + lhi*4 + jj)*520 + jcol] = pb;
          p4[jj] = pb;
        }
        s16x4 v4 = {(short)p4[0],(short)p4[1],(short)p4[2],(short)p4[3]};
        *(s16x4*)&PpT[(size_t)jcol*40 + rt*16 + lhi*4] = v4;
      }
    }
    __syncthreads();
    // ---- mi: (h,wr,wc) split, half-K each; B from t2s (LDS) ----
    {
      int h = w>>3, wr = (w>>2)&1, wc = w&3;
      f32x4 mia = {0.f,0.f,0.f,0.f};
      const u16* Ab = Pp + (wr*16 + l15)*520 + h*256 + lhi*8;
      const u16* Bb = t2s + (wc*16 + l15)*520 + h*256 + lhi*8;
      #pragma unroll
      for(int ks=0;ks<8;ks++)
        mia = MFMA(ldb8(Ab + ks*32), ldb8(Bb + ks*32), mia);
      #pragma unroll
      for(int jj=0;jj<4;jj++)
        stgf[(h*32 + wr*16 + lhi*4 + jj)*68 + wc*16 + l15] = mia[jj];
    }
    // ---- mj accumulate: K=32 (this panel), A = PpT, B = t1t ----
    {
      bf16x8 av[2];
      #pragma unroll
      for(int jt=0;jt<2;jt++)
        av[jt] = ldb8(PpT + (size_t)(jc0 + jt*16 + l15)*40 + lhi*8);
      #pragma unroll
      for(int bt=0;bt<4;bt++){
        bf16x8 b = ldb8(t1t + ((size_t)zc*64 + bt*16 + l15)*LL + i0g + lhi*8);
        #pragma unroll
        for(int jt=0;jt<2;jt++) mj[jt][bt] = MFMA(av[jt], b, mj[jt][bt]);
      }
    }
    __syncthreads();
    // ---- mi store: sum 2 K-halves, 16B coalesced ----
    if(t < 512){
      int r = t>>4, cc = t&15;
      f32x4 v0 = *(const f32x4*)&stgf[r*68 + cc*4];
      f32x4 v1 = *(const f32x4*)&stgf[(32+r)*68 + cc*4];
      s16x4 o = { (short)f2b(v0[0]+v1[0]), (short)f2b(v0[1]+v1[1]),
                  (short)f2b(v0[2]+v1[2]), (short)f2b(v0[3]+v1[3]) };
      *(s16x4*)&miP[((size_t)z*LL + i0g + r)*512 + c*64 + cc*4] = o;
    }
    __syncthreads();
  }
  // ---- mj dump: 4 rounds of 128 j-rows via LDS, 16B coalesced ----
  for(int r=0;r<4;r++){
    if((w>>2) == r){
      int jl = (w&3)*32;
      #pragma unroll
      for(int jt=0;jt<2;jt++)
        #pragma unroll
        for(int bt=0;bt<4;bt++)
          #pragma unroll
          for(int jj=0;jj<4;jj++)
            stg[(jl + jt*16 + lhi*4 + jj)*72 + bt*16 + l15] = f2b(mj[jt][bt][jj]);
    }
    __syncthreads();
    {
      int jr = t>>3, ch = t&7;
      *(bf16x8*)&mjP[(((size_t)(it*8 + z))*LL + r*128 + jr)*512 + c*64 + ch*8]
        = *(const bf16x8*)&stg[jr*72 + ch*8];
    }
    __syncthreads();
  }
}

// ---- k5c: out = (unary + Mg + sum_c miP + sum_{it,c} mjP) * m1  (elementwise) ----
__global__ __launch_bounds__(256) void k5c(const u16* __restrict__ miP, const u16* __restrict__ mjP,
      const float* __restrict__ MgF, const float* __restrict__ unary, const float* __restrict__ mf,
      float* __restrict__ outq){
  int bid = blockIdx.x; int z = bid&7, itile = bid>>3;   // itile < 16
  int t = threadIdx.x;
  int r = t>>3, c8 = t&7;
  int row = itile*32 + r;
  size_t gr = (size_t)z*LL + row;
  const float* mgp = &MgF[gr*64 + c8*8];
  f32x4 aclo = *(const f32x4*)mgp;
  f32x4 achi = *(const f32x4*)(mgp + 4);
  #pragma unroll
  for(int c=0;c<8;c++){
    bf16x8 v = ldb8(&miP[gr*512 + c*64 + c8*8]);
    aclo[0]+=b2f((u16)v[0]); aclo[1]+=b2f((u16)v[1]); aclo[2]+=b2f((u16)v[2]); aclo[3]+=b2f((u16)v[3]);
    achi[0]+=b2f((u16)v[4]); achi[1]+=b2f((u16)v[5]); achi[2]+=b2f((u16)v[6]); achi[3]+=b2f((u16)v[7]);
  }
  #pragma unroll
  for(int s=0;s<4;s++)
    #pragma unroll
    for(int c=0;c<8;c++){
      bf16x8 v = ldb8(&mjP[(((size_t)(s*8 + z))*LL + row)*512 + c*64 + c8*8]);
      aclo[0]+=b2f((u16)v[0]); aclo[1]+=b2f((u16)v[1]); aclo[2]+=b2f((u16)v[2]); aclo[3]+=b2f((u16)v[3]);
      achi[0]+=b2f((u16)v[4]); achi[1]+=b2f((u16)v[5]); achi[2]+=b2f((u16)v[6]); achi[3]+=b2f((u16)v[7]);
    }
  f32x4 u0 = *(const f32x4*)&unary[gr*64 + c8*8];
  f32x4 u1 = *(const f32x4*)&unary[gr*64 + c8*8 + 4];
  float mk = mf[gr];
  f32x4 o0, o1;
  #pragma unroll
  for(int k=0;k<4;k++){ o0[k] = (u0[k] + aclo[k]) * mk; o1[k] = (u1[k] + achi[k]) * mk; }
  *(f32x4*)&outq[gr*64 + c8*8]     = o0;
  *(f32x4*)&outq[gr*64 + c8*8 + 4] = o1;
}

extern "C" void kernel_launch(void* const* d_in, const int* in_sizes, int n_in,
                              void* d_out, int out_size, void* d_ws, size_t ws_size,
                              hipStream_t stream) {
  const float* x       = (const float*)d_in[0];
  const int*   mask    = (const int*)d_in[1];
  const float* ternary = (const float*)d_in[2];
  const float* gw      = (const float*)d_in[3];
  float* out = (float*)d_out;

  const size_t NE = (size_t)BB*LL*64;          // 262144
  char* p = (char*)d_ws;
  auto alloc = [&](size_t bytes)->void*{
    void* r = (void*)p; p += (bytes + 255) & ~(size_t)255; return r;
  };
  float* unary   = (float*)alloc(NE*4);
  float* qzstate = (float*)alloc(NE*4);
  float* mf      = (float*)alloc((size_t)BB*LL*4);
  u16*   qzb     = (u16*)alloc(NE*2);
  u16*   t1b     = (u16*)alloc((size_t)BB*HH*LL*64*2);   // 4.2 MB
  u16*   t1t     = (u16*)alloc((size_t)BB*HH*LL*64*2);   // 4.2 MB
  u16*   t2t     = (u16*)alloc((size_t)BB*HH*LL*64*2);   // 4.2 MB
  float* MgF     = (float*)alloc(NE*4);                  // 1 MB
  u16*   miP     = (u16*)alloc((size_t)BB*LL*512*2);     // 4.2 MB
  u16*   mjP     = (u16*)alloc((size_t)32*LL*512*2);     // 16.8 MB
  u16*   T4t     = (u16*)alloc(32768*2);
  u16*   Tt2     = (u16*)alloc(32768*2);
  u16*   Gt      = (u16*)alloc(4096*2);
  u16*   Gt2     = (u16*)alloc(4096*2);

  const int KF_LDS = 161280;   // t2s 66560 + Pp 33280 + PpT 40960 + red 2048 + stg 18432
  hipFuncSetAttribute(reinterpret_cast<const void*>(kF),
                      hipFuncAttributeMaxDynamicSharedMemorySize, KF_LDS);

  kp_prep<<<128, 256, 0, stream>>>(ternary, gw, T4t, Tt2, Gt, Gt2);
  k0_init<<<(int)(NE/256), 256, 0, stream>>>(x, mask, unary, qzstate, mf);
  for(int it=0; it<4; ++it){
    kA<<<BB*8, 256, 0, stream>>>(qzstate, mask, Gt2, Gt, qzb, MgF);
    k2<<<512, 256, 0, stream>>>(qzb, T4t, Tt2, t1b, t1t, t2t);
    kF<<<256, 1024, KF_LDS, stream>>>(t1b, qzb, t1t, t2t, mf, miP, mjP);
    float* outq = (it==3) ? out : qzstate;
    k5c<<<128, 256, 0, stream>>>(miP, mjP, MgF, unary, mf, outq);
  }
}